// Round 2
// baseline (209.548 us; speedup 1.0000x reference)
//
#include <hip/hip_runtime.h>

#define LN_EPS 1e-5f

typedef short bf16x8 __attribute__((ext_vector_type(8)));
typedef float f32x4  __attribute__((ext_vector_type(4)));

__device__ __forceinline__ unsigned short f2bf(float f) {
  unsigned u = __float_as_uint(f);
  u += 0x7fffu + ((u >> 16) & 1u);          // RNE
  return (unsigned short)(u >> 16);
}
__device__ __forceinline__ float bf2f(unsigned short s) {
  return __uint_as_float(((unsigned)s) << 16);
}
__device__ __forceinline__ int swz(int r) { return (r ^ (r >> 2)) & 3; }

__device__ __forceinline__ bf16x8 pack8(float4 a, float4 b) {
  bf16x8 v;
  v[0] = (short)f2bf(a.x); v[1] = (short)f2bf(a.y);
  v[2] = (short)f2bf(a.z); v[3] = (short)f2bf(a.w);
  v[4] = (short)f2bf(b.x); v[5] = (short)f2bf(b.y);
  v[6] = (short)f2bf(b.z); v[7] = (short)f2bf(b.w);
  return v;
}

// async 16B/lane global->LDS: lds dst is wave-uniform base (+lane*16 by HW)
__device__ __forceinline__ void ldst16(const unsigned short* g, unsigned short* l) {
  __builtin_amdgcn_global_load_lds(
      (const __attribute__((address_space(1))) unsigned int*)g,
      (__attribute__((address_space(3))) unsigned int*)l, 16, 0, 0);
}

// ---------------------------------------------------------------------------
// Prep: build BT = pre-tiled bf16 image of [W_in (chunks 0..7) | CB (chunks
// 8..23)], 16KB per chunk, layout row*64B + ((kq ^ swz(row))*16B) so main can
// global_load_lds it verbatim.  Also c2, code_out = CB@W_out^T (LDS-tiled,
// coalesced), and zero loss/ticket.
// blocks: [0,32) W_in tiles; [32,96) CB tiles + c2; [96,352) code_out
// ---------------------------------------------------------------------------
__global__ __launch_bounds__(256) void prep_kernel(
    const float* __restrict__ codebook, const float* __restrict__ W_in,
    const float* __restrict__ W_out,
    float* __restrict__ loss_acc, unsigned* __restrict__ ticket,
    float* __restrict__ c2, float* __restrict__ code_out,
    unsigned short* __restrict__ BT) {
  const int b = blockIdx.x, t = threadIdx.x;
  if (b < 32) {
    if (b == 0 && t == 0) { *loss_acc = 0.f; *ticket = 0u; }
    int e = b * 8 + (t >> 5);
    int c32 = t & 31, ks = c32 >> 2, kq = c32 & 3;
    const float* src = W_in + e * 256 + c32 * 8;
    float4 x0 = *(const float4*)src, x1 = *(const float4*)(src + 4);
    *(bf16x8*)(BT + ks * 8192 + e * 32 + ((kq ^ swz(e)) * 8)) = pack8(x0, x1);
  } else if (b < 96) {
    int code = (b - 32) * 8 + (t >> 5);
    int c32 = t & 31, ks = c32 >> 2, kq = c32 & 3;
    const float* src = codebook + code * 256 + c32 * 8;
    float4 x0 = *(const float4*)src, x1 = *(const float4*)(src + 4);
    int rl = code & 255;
    int chunk = 8 + (code >> 8) * 8 + ks;
    *(bf16x8*)(BT + chunk * 8192 + rl * 32 + ((kq ^ swz(rl)) * 8)) = pack8(x0, x1);
    float s = x0.x * x0.x + x0.y * x0.y + x0.z * x0.z + x0.w * x0.w +
              x1.x * x1.x + x1.y * x1.y + x1.z * x1.z + x1.w * x1.w;
    s += __shfl_xor(s, 1);  s += __shfl_xor(s, 2);
    s += __shfl_xor(s, 4);  s += __shfl_xor(s, 8);
    s += __shfl_xor(s, 16);
    if ((t & 31) == 0) c2[code] = s;
  } else {
    // code_out tile: 32 codes x 16 e-rows per block; both operands LDS-staged
    __shared__ float Cs[32][260];
    __shared__ float Ws[16][260];
    int bi = b - 96, ci = bi & 15, ei = bi >> 4;
    {
      int row = t >> 4, col = (t & 15) * 16;
      const float4* s = (const float4*)(W_out + (size_t)(ei * 16 + row) * 256 + col);
      float4* d = (float4*)&Ws[row][col];
      d[0] = s[0]; d[1] = s[1]; d[2] = s[2]; d[3] = s[3];
    }
    {
      int row = t >> 3, col = (t & 7) * 32;
      const float4* s = (const float4*)(codebook + (size_t)(ci * 32 + row) * 256 + col);
      float4* d = (float4*)&Cs[row][col];
      #pragma unroll
      for (int k = 0; k < 8; k++) d[k] = s[k];
    }
    __syncthreads();
    int c = t & 31, e0 = t >> 5;
    float a0 = 0.f, a1 = 0.f;
    #pragma unroll 4
    for (int d = 0; d < 256; d += 4) {
      float4 cv = *(const float4*)&Cs[c][d];
      float4 w0 = *(const float4*)&Ws[e0][d];
      float4 w1 = *(const float4*)&Ws[e0 + 8][d];
      a0 += cv.x * w0.x + cv.y * w0.y + cv.z * w0.z + cv.w * w0.w;
      a1 += cv.x * w1.x + cv.y * w1.y + cv.z * w1.z + cv.w * w1.w;
    }
    code_out[(size_t)(ci * 32 + c) * 256 + ei * 16 + e0]     = a0;
    code_out[(size_t)(ci * 32 + c) * 256 + ei * 16 + e0 + 8] = a1;
  }
}

// ---------------------------------------------------------------------------
// Main fused kernel: 64 rows/block, 256 threads (4 waves), 2 blocks/CU.
// Uniform 24-chunk K-loop (8 W_in + 16 CB), wave-private B staging via
// global_load_lds double-buffer -> NO per-iteration __syncthreads.
// ---------------------------------------------------------------------------
__global__ __launch_bounds__(256, 2) void main_kernel(
    const float* __restrict__ hidden, const int* __restrict__ mask,
    const float* __restrict__ gamma, const float* __restrict__ beta,
    const float* __restrict__ c2g, const float* __restrict__ code_out,
    const unsigned short* __restrict__ BT,
    float* __restrict__ loss_acc, unsigned* __restrict__ ticket,
    float* __restrict__ out) {

  __shared__ unsigned short HZ[64 * 264];      // H then Z (33792 B), stride 264
  __shared__ unsigned short Bbuf[2][8192];     // 2 x 16 KB B-tiles
  __shared__ float c2s[512];
  __shared__ float z2[64];
  __shared__ float sminv[256];
  __shared__ int   sminc[256];
  __shared__ int   ridx[64];

  const int t    = threadIdx.x;
  const int lane = t & 63;
  const int w    = t >> 6;
  const int l15  = lane & 15;
  const int quad = lane >> 4;
  const int row0 = blockIdx.x * 64;

  c2s[t]       = c2g[t];
  c2s[t + 256] = c2g[t + 256];

  // ---- stage H (hidden block, fp32->bf16) ----
  {
    int r = t >> 2, q4 = t & 3;
    const float* src = hidden + (size_t)(row0 + r) * 256 + q4 * 64;
    unsigned short* dst = HZ + r * 264 + q4 * 64;
    #pragma unroll
    for (int j = 0; j < 8; j++) {
      float4 x0 = *(const float4*)(src + j * 8);
      float4 x1 = *(const float4*)(src + j * 8 + 4);
      *(bf16x8*)(dst + j * 8) = pack8(x0, x1);
    }
  }
  __syncthreads();   // H visible to all waves

  const f32x4 zf = {0.f, 0.f, 0.f, 0.f};
  f32x4 acc[4][4];
  #pragma unroll
  for (int i = 0; i < 4; i++)
    #pragma unroll
    for (int j = 0; j < 4; j++) acc[i][j] = zf;

  float runv[16];
  int   runc[16];
  #pragma unroll
  for (int r = 0; r < 16; r++) { runv[r] = 3.4e38f; runc[r] = 0; }

  // issue chunk0 into buf0 (wave-private quarter)
  {
    const unsigned short* g = BT + w * 2048 + lane * 8;
    unsigned short* l = &Bbuf[0][w * 2048];
    #pragma unroll
    for (int q = 0; q < 4; q++) ldst16(g + q * 512, l + q * 512);
  }

  for (int chunk = 0; chunk < 24; chunk++) {
    const int cu = chunk & 1;
    if (chunk == 8) {
      // phase 1 -> phase 2 transition
      __builtin_amdgcn_s_waitcnt(0x0F70);   // my buf[cu] loads done
      __syncthreads();                       // all waves' H reads done
      // Z epilogue: C/D layout row=quad*4+reg, col=lane&15
      #pragma unroll
      for (int i = 0; i < 4; i++)
        #pragma unroll
        for (int j = 0; j < 4; j++)
          #pragma unroll
          for (int r = 0; r < 4; r++)
            HZ[(i * 16 + quad * 4 + r) * 264 + (w * 64 + j * 16 + l15)] =
                f2bf(acc[i][j][r]);
      __syncthreads();                       // Z visible
      { // |z|^2 per row from bf16 Z (consistent with scores)
        int zr = t >> 2, part = t & 3;
        float s = 0.f;
        const unsigned short* zp = HZ + zr * 264 + part * 64;
        #pragma unroll
        for (int c = 0; c < 64; c += 8) {
          bf16x8 v = *(const bf16x8*)(zp + c);
          #pragma unroll
          for (int e = 0; e < 8; e++) { float f = bf2f((unsigned short)v[e]); s += f * f; }
        }
        s += __shfl_xor(s, 1);
        s += __shfl_xor(s, 2);
        if (part == 0) z2[zr] = s;
      }
      #pragma unroll
      for (int i = 0; i < 4; i++)
        #pragma unroll
        for (int j = 0; j < 4; j++) acc[i][j] = zf;
    } else {
      __builtin_amdgcn_s_waitcnt(0x0F70);   // wait only vmcnt(0): my buf[cu] ready
    }

    if (chunk < 23) { // prefetch next chunk into other buffer (wave-private)
      const unsigned short* g = BT + (chunk + 1) * 8192 + w * 2048 + lane * 8;
      unsigned short* l = &Bbuf[cu ^ 1][w * 2048];
      #pragma unroll
      for (int q = 0; q < 4; q++) ldst16(g + q * 512, l + q * 512);
    }

    const int ks = chunk & 7;
    bf16x8 a[4];
    #pragma unroll
    for (int i = 0; i < 4; i++)
      a[i] = *(const bf16x8*)(HZ + (i * 16 + l15) * 264 + ks * 32 + quad * 8);
    #pragma unroll
    for (int j = 0; j < 4; j++) {
      int c = w * 64 + j * 16 + l15;
      bf16x8 bb = *(const bf16x8*)(&Bbuf[cu][c * 32 + ((quad ^ swz(c)) * 8)]);
      #pragma unroll
      for (int i = 0; i < 4; i++)
        acc[i][j] = __builtin_amdgcn_mfma_f32_16x16x32_bf16(a[i], bb, acc[i][j], 0, 0, 0);
    }

    if (chunk == 15 || chunk == 23) {  // fold scores of this pass
      int pass = (chunk - 8) >> 3;
      #pragma unroll
      for (int i = 0; i < 4; i++)
        #pragma unroll
        for (int j = 0; j < 4; j++) {
          int code = pass * 256 + w * 64 + j * 16 + l15;
          float cc = c2s[code];
          #pragma unroll
          for (int r = 0; r < 4; r++) {
            float s = cc - 2.f * acc[i][j][r];
            int ri = i * 4 + r;
            if (s < runv[ri]) { runv[ri] = s; runc[ri] = code; }
          }
        }
      if (chunk == 15) {
        #pragma unroll
        for (int i = 0; i < 4; i++)
          #pragma unroll
          for (int j = 0; j < 4; j++) acc[i][j] = zf;
      }
    }
  }

  // ---- argmin reduce across 16 lanes of each quad group ----
  #pragma unroll
  for (int ri = 0; ri < 16; ri++) {
    float v = runv[ri]; int c = runc[ri];
    #pragma unroll
    for (int m = 1; m < 16; m <<= 1) {
      float ov = __shfl_xor(v, m);
      int   oc = __shfl_xor(c, m);
      if (ov < v || (ov == v && oc < c)) { v = ov; c = oc; }
    }
    if (l15 == 0) {
      int i = ri >> 2, r = ri & 3;
      int row = i * 16 + quad * 4 + r;
      sminv[w * 64 + row] = v;
      sminc[w * 64 + row] = c;
    }
  }
  __syncthreads();

  if (t < 64) { // merge 4 waves, finalize idx + dist, block loss + ticket
    int row = t;
    float bv = sminv[row]; int bc = sminc[row];
    #pragma unroll
    for (int ww = 1; ww < 4; ww++) {
      float v = sminv[ww * 64 + row]; int c = sminc[ww * 64 + row];
      if (v < bv || (v == bv && c < bc)) { bv = v; bc = c; }
    }
    ridx[row] = bc;
    float dist = z2[row] + bv;
    #pragma unroll
    for (int m = 1; m < 64; m <<= 1) dist += __shfl_xor(dist, m);
    if (t == 0) {
      atomicAdd(loss_acc, dist);
      __threadfence();
      unsigned done = atomicAdd(ticket, 1u);
      if (done == gridDim.x - 1) {
        float total = atomicAdd(loss_acc, 0.f);
        out[16777216] = 1.25f * total * (1.f / 16777216.f);
      }
    }
  }
  __syncthreads();

  // ---- phase 3: h = hidden + mask*code_out[idx]; LayerNorm; store ----
  {
    float4 g4 = *(const float4*)(gamma + lane * 4);
    float4 b4 = *(const float4*)(beta + lane * 4);
    for (int rr = 0; rr < 16; rr++) {
      int row = w * 16 + rr;
      int gr  = row0 + row;
      float4 h = *(const float4*)(hidden + (size_t)gr * 256 + lane * 4);
      int code = ridx[row];
      float4 o = *(const float4*)(code_out + (size_t)code * 256 + lane * 4);
      float mf = mask[gr] ? 1.f : 0.f;
      h.x += mf * o.x; h.y += mf * o.y; h.z += mf * o.z; h.w += mf * o.w;
      float s  = h.x + h.y + h.z + h.w;
      float sq = h.x * h.x + h.y * h.y + h.z * h.z + h.w * h.w;
      #pragma unroll
      for (int m = 1; m < 64; m <<= 1) { s += __shfl_xor(s, m); sq += __shfl_xor(sq, m); }
      float mean = s * (1.f / 256.f);
      float var  = sq * (1.f / 256.f) - mean * mean;
      float rstd = rsqrtf(var + LN_EPS);
      float4 res;
      res.x = (h.x - mean) * rstd * g4.x + b4.x;
      res.y = (h.y - mean) * rstd * g4.y + b4.y;
      res.z = (h.z - mean) * rstd * g4.z + b4.z;
      res.w = (h.w - mean) * rstd * g4.w + b4.w;
      *(float4*)(out + (size_t)gr * 256 + lane * 4) = res;
    }
  }
}

extern "C" void kernel_launch(void* const* d_in, const int* in_sizes, int n_in,
                              void* d_out, int out_size, void* d_ws, size_t ws_size,
                              hipStream_t stream) {
  (void)in_sizes; (void)n_in; (void)out_size; (void)ws_size;
  const float* hidden   = (const float*)d_in[0];
  const int*   mask     = (const int*)d_in[1];
  const float* codebook = (const float*)d_in[2];
  const float* W_in     = (const float*)d_in[3];
  const float* W_out    = (const float*)d_in[4];
  const float* gamma    = (const float*)d_in[5];
  const float* beta     = (const float*)d_in[6];
  float* out = (float*)d_out;

  float* wsf      = (float*)d_ws;
  float* loss_acc = wsf;                        // [1]
  unsigned* ticket = (unsigned*)(wsf + 1);      // [1]
  float* c2       = wsf + 64;                   // [512]
  float* code_out = wsf + 64 + 512;             // [512*256]
  unsigned short* BT = (unsigned short*)(wsf + 64 + 512 + 512 * 256); // 24*8192 bf16

  prep_kernel<<<352, 256, 0, stream>>>(codebook, W_in, W_out, loss_acc, ticket,
                                       c2, code_out, BT);
  main_kernel<<<1024, 256, 0, stream>>>(hidden, mask, gamma, beta, c2, code_out,
                                        BT, loss_acc, ticket, out);
}

// Round 3
// 196.514 us; speedup vs baseline: 1.0663x; 1.0663x over previous
//
#include <hip/hip_runtime.h>

#define LN_EPS 1e-5f

typedef short bf16x8 __attribute__((ext_vector_type(8)));
typedef float f32x4  __attribute__((ext_vector_type(4)));

__device__ __forceinline__ unsigned short f2bf(float f) {
  unsigned u = __float_as_uint(f);
  u += 0x7fffu + ((u >> 16) & 1u);          // RNE
  return (unsigned short)(u >> 16);
}
__device__ __forceinline__ float bf2f(unsigned short s) {
  return __uint_as_float(((unsigned)s) << 16);
}

__device__ __forceinline__ bf16x8 pack8(float4 a, float4 b) {
  bf16x8 v;
  v[0] = (short)f2bf(a.x); v[1] = (short)f2bf(a.y);
  v[2] = (short)f2bf(a.z); v[3] = (short)f2bf(a.w);
  v[4] = (short)f2bf(b.x); v[5] = (short)f2bf(b.y);
  v[6] = (short)f2bf(b.z); v[7] = (short)f2bf(b.w);
  return v;
}

// ---------------------------------------------------------------------------
// Prep: BT = pre-tiled bf16 image of [W_in: chunks 0..7 | CB: chunks 8..23].
// Chunk layout (shorts): chunk*8192 + w*2048 + j*512 + quad*128 + l15*8
// so main's b-frag for (col = w*64+j*16+l15, k = chunk_k*32+quad*8..) is one
// contiguous 16B load at  chunk*8192 + w*2048 + j*512 + lane*8.
// Also c2 (fp32), code_out = CB@W_out^T, loss/ticket zero.
// blocks: [0,32) W_in; [32,96) CB + c2; [96,352) code_out
// ---------------------------------------------------------------------------
__global__ __launch_bounds__(256) void prep_kernel(
    const float* __restrict__ codebook, const float* __restrict__ W_in,
    const float* __restrict__ W_out,
    float* __restrict__ loss_acc, unsigned* __restrict__ ticket,
    float* __restrict__ c2, float* __restrict__ code_out,
    unsigned short* __restrict__ BT) {
  const int b = blockIdx.x, t = threadIdx.x;
  if (b < 32) {
    if (b == 0 && t == 0) { *loss_acc = 0.f; *ticket = 0u; }
    int e = b * 8 + (t >> 5);
    int c32 = t & 31, ks = c32 >> 2, kq = c32 & 3;
    const float* src = W_in + e * 256 + c32 * 8;
    float4 x0 = *(const float4*)src, x1 = *(const float4*)(src + 4);
    *(bf16x8*)(BT + ks * 8192 + (e >> 6) * 2048 + ((e >> 4) & 3) * 512 +
               kq * 128 + (e & 15) * 8) = pack8(x0, x1);
  } else if (b < 96) {
    int code = (b - 32) * 8 + (t >> 5);
    int c32 = t & 31, ks = c32 >> 2, kq = c32 & 3;
    const float* src = codebook + code * 256 + c32 * 8;
    float4 x0 = *(const float4*)src, x1 = *(const float4*)(src + 4);
    int cl = code & 255;
    int chunk = 8 + (code >> 8) * 8 + ks;
    *(bf16x8*)(BT + chunk * 8192 + (cl >> 6) * 2048 + ((cl >> 4) & 3) * 512 +
               kq * 128 + (cl & 15) * 8) = pack8(x0, x1);
    float s = x0.x * x0.x + x0.y * x0.y + x0.z * x0.z + x0.w * x0.w +
              x1.x * x1.x + x1.y * x1.y + x1.z * x1.z + x1.w * x1.w;
    s += __shfl_xor(s, 1);  s += __shfl_xor(s, 2);
    s += __shfl_xor(s, 4);  s += __shfl_xor(s, 8);
    s += __shfl_xor(s, 16);
    if ((t & 31) == 0) c2[code] = s;
  } else {
    // code_out tile: 32 codes x 16 e-rows per block; both operands LDS-staged
    __shared__ float Cs[32][260];
    __shared__ float Ws[16][260];
    int bi = b - 96, ci = bi & 15, ei = bi >> 4;
    {
      int row = t >> 4, col = (t & 15) * 16;
      const float4* s = (const float4*)(W_out + (size_t)(ei * 16 + row) * 256 + col);
      float4* d = (float4*)&Ws[row][col];
      d[0] = s[0]; d[1] = s[1]; d[2] = s[2]; d[3] = s[3];
    }
    {
      int row = t >> 3, col = (t & 7) * 32;
      const float4* s = (const float4*)(codebook + (size_t)(ci * 32 + row) * 256 + col);
      float4* d = (float4*)&Cs[row][col];
      #pragma unroll
      for (int k = 0; k < 8; k++) d[k] = s[k];
    }
    __syncthreads();
    int c = t & 31, e0 = t >> 5;
    float a0 = 0.f, a1 = 0.f;
    #pragma unroll 4
    for (int d = 0; d < 256; d += 4) {
      float4 cv = *(const float4*)&Cs[c][d];
      float4 w0 = *(const float4*)&Ws[e0][d];
      float4 w1 = *(const float4*)&Ws[e0 + 8][d];
      a0 += cv.x * w0.x + cv.y * w0.y + cv.z * w0.z + cv.w * w0.w;
      a1 += cv.x * w1.x + cv.y * w1.y + cv.z * w1.z + cv.w * w1.w;
    }
    code_out[(size_t)(ci * 32 + c) * 256 + ei * 16 + e0]     = a0;
    code_out[(size_t)(ci * 32 + c) * 256 + ei * 16 + e0 + 8] = a1;
  }
}

// ---------------------------------------------------------------------------
// Main fused kernel: 64 rows/block, 256 threads (4 waves), 3 blocks/CU.
// B streamed straight from global (L2/L3-hot pre-tiled image) into VGPRs;
// only H/Z live in LDS.  Argmin state packed (dist|code) into one uint.
// ---------------------------------------------------------------------------
__global__ __launch_bounds__(256, 3) void main_kernel(
    const float* __restrict__ hidden, const int* __restrict__ mask,
    const float* __restrict__ gamma, const float* __restrict__ beta,
    const float* __restrict__ c2g, const float* __restrict__ code_out,
    const unsigned short* __restrict__ BT,
    float* __restrict__ loss_acc, unsigned* __restrict__ ticket,
    float* __restrict__ out) {

  __shared__ unsigned short HZ[64 * 264];   // H then Z (33792 B), stride 264
  __shared__ float    z2[64];
  __shared__ unsigned sminp[256];
  __shared__ int      ridx[64];

  const int t    = threadIdx.x;
  const int lane = t & 63;
  const int w    = t >> 6;
  const int l15  = lane & 15;
  const int quad = lane >> 4;
  const int row0 = blockIdx.x * 64;

  // c2 for this wave's code columns (both passes), 8 coalesced floats
  float ccp[2][4];
  #pragma unroll
  for (int p = 0; p < 2; p++)
    #pragma unroll
    for (int j = 0; j < 4; j++)
      ccp[p][j] = c2g[p * 256 + w * 64 + j * 16 + l15];

  // ---- stage H: wave-contiguous 2KB global reads, b128 LDS writes ----
  {
    #pragma unroll
    for (int i = 0; i < 8; i++) {
      int flat = (t * 8) + i * 2048;          // float index in 64x256 tile
      int r = flat >> 8, c = flat & 255;
      const float* src = hidden + (size_t)row0 * 256 + flat;
      float4 x0 = *(const float4*)src, x1 = *(const float4*)(src + 4);
      *(bf16x8*)(HZ + r * 264 + c) = pack8(x0, x1);
    }
  }
  __syncthreads();   // H visible

  const f32x4 zf = {0.f, 0.f, 0.f, 0.f};
  f32x4 acc[4][4];
  #pragma unroll
  for (int i = 0; i < 4; i++)
    #pragma unroll
    for (int j = 0; j < 4; j++) acc[i][j] = zf;

  // ---------------- Phase 1: Z = H * W_in^T ----------------
  const unsigned short* BTw = BT + w * 2048 + lane * 8;
  #pragma unroll 2
  for (int ks = 0; ks < 8; ks++) {
    const unsigned short* bp = BTw + ks * 8192;
    bf16x8 b0 = *(const bf16x8*)(bp);
    bf16x8 b1 = *(const bf16x8*)(bp + 512);
    bf16x8 b2 = *(const bf16x8*)(bp + 1024);
    bf16x8 b3 = *(const bf16x8*)(bp + 1536);
    bf16x8 a[4];
    #pragma unroll
    for (int i = 0; i < 4; i++)
      a[i] = *(const bf16x8*)(HZ + (i * 16 + l15) * 264 + ks * 32 + quad * 8);
    #pragma unroll
    for (int i = 0; i < 4; i++) {
      acc[i][0] = __builtin_amdgcn_mfma_f32_16x16x32_bf16(a[i], b0, acc[i][0], 0, 0, 0);
      acc[i][1] = __builtin_amdgcn_mfma_f32_16x16x32_bf16(a[i], b1, acc[i][1], 0, 0, 0);
      acc[i][2] = __builtin_amdgcn_mfma_f32_16x16x32_bf16(a[i], b2, acc[i][2], 0, 0, 0);
      acc[i][3] = __builtin_amdgcn_mfma_f32_16x16x32_bf16(a[i], b3, acc[i][3], 0, 0, 0);
    }
  }

  __syncthreads();   // all H reads done
  // Z epilogue: C/D layout row = quad*4+reg, col = lane&15
  #pragma unroll
  for (int i = 0; i < 4; i++)
    #pragma unroll
    for (int j = 0; j < 4; j++)
      #pragma unroll
      for (int r = 0; r < 4; r++)
        HZ[(i * 16 + quad * 4 + r) * 264 + (w * 64 + j * 16 + l15)] =
            f2bf(acc[i][j][r]);
  __syncthreads();   // Z visible

  { // |z|^2 per row from bf16 Z (consistent with scores)
    int zr = t >> 2, part = t & 3;
    float s = 0.f;
    const unsigned short* zp = HZ + zr * 264 + part * 64;
    #pragma unroll
    for (int c = 0; c < 64; c += 8) {
      bf16x8 v = *(const bf16x8*)(zp + c);
      #pragma unroll
      for (int e = 0; e < 8; e++) { float f = bf2f((unsigned short)v[e]); s += f * f; }
    }
    s += __shfl_xor(s, 1);
    s += __shfl_xor(s, 2);
    if (part == 0) z2[zr] = s;
  }

  // ---------------- Phase 2: scores + packed argmin ----------------
  unsigned runp[16];
  #pragma unroll
  for (int r = 0; r < 16; r++) runp[r] = 0xFFFFFFFFu;

  for (int pass = 0; pass < 2; pass++) {
    #pragma unroll
    for (int i = 0; i < 4; i++)
      #pragma unroll
      for (int j = 0; j < 4; j++) acc[i][j] = zf;

    #pragma unroll 2
    for (int ks = 0; ks < 8; ks++) {
      const unsigned short* bp = BTw + (8 + pass * 8 + ks) * 8192;
      bf16x8 b0 = *(const bf16x8*)(bp);
      bf16x8 b1 = *(const bf16x8*)(bp + 512);
      bf16x8 b2 = *(const bf16x8*)(bp + 1024);
      bf16x8 b3 = *(const bf16x8*)(bp + 1536);
      bf16x8 a[4];
      #pragma unroll
      for (int i = 0; i < 4; i++)
        a[i] = *(const bf16x8*)(HZ + (i * 16 + l15) * 264 + ks * 32 + quad * 8);
      #pragma unroll
      for (int i = 0; i < 4; i++) {
        acc[i][0] = __builtin_amdgcn_mfma_f32_16x16x32_bf16(a[i], b0, acc[i][0], 0, 0, 0);
        acc[i][1] = __builtin_amdgcn_mfma_f32_16x16x32_bf16(a[i], b1, acc[i][1], 0, 0, 0);
        acc[i][2] = __builtin_amdgcn_mfma_f32_16x16x32_bf16(a[i], b2, acc[i][2], 0, 0, 0);
        acc[i][3] = __builtin_amdgcn_mfma_f32_16x16x32_bf16(a[i], b3, acc[i][3], 0, 0, 0);
      }
    }
    // fold: m = c2 - 2 z.c ; pack sortable (dist | 9-bit code); min
    #pragma unroll
    for (int i = 0; i < 4; i++)
      #pragma unroll
      for (int j = 0; j < 4; j++) {
        int code = pass * 256 + w * 64 + j * 16 + l15;
        float cc = ccp[pass][j];
        #pragma unroll
        for (int r = 0; r < 4; r++) {
          float m = cc - 2.f * acc[i][j][r];
          unsigned bits = __float_as_uint(m);
          unsigned u = bits ^ (0x80000000u | (unsigned)((int)bits >> 31));
          unsigned p = (u & 0xFFFFFE00u) | (unsigned)code;
          int ri = i * 4 + r;
          runp[ri] = min(runp[ri], p);
        }
      }
  }

  // reduce across the 16 lanes of each quad group
  #pragma unroll
  for (int ri = 0; ri < 16; ri++) {
    unsigned v = runp[ri];
    v = min(v, (unsigned)__shfl_xor((int)v, 1));
    v = min(v, (unsigned)__shfl_xor((int)v, 2));
    v = min(v, (unsigned)__shfl_xor((int)v, 4));
    v = min(v, (unsigned)__shfl_xor((int)v, 8));
    if (l15 == 0) {
      int i = ri >> 2, r = ri & 3;
      sminp[w * 64 + (i * 16 + quad * 4 + r)] = v;
    }
  }
  __syncthreads();

  if (t < 64) { // merge 4 waves, finalize idx + dist, block loss + ticket
    int row = t;
    unsigned bv = sminp[row];
    bv = min(bv, sminp[64 + row]);
    bv = min(bv, sminp[128 + row]);
    bv = min(bv, sminp[192 + row]);
    ridx[row] = (int)(bv & 511u);
    unsigned u = bv & 0xFFFFFE00u;
    unsigned bits = (u & 0x80000000u) ? (u ^ 0x80000000u) : ~u;
    float dist = z2[row] + __uint_as_float(bits);
    #pragma unroll
    for (int m = 1; m < 64; m <<= 1) dist += __shfl_xor(dist, m);
    if (t == 0) {
      atomicAdd(loss_acc, dist);
      __threadfence();
      unsigned done = atomicAdd(ticket, 1u);
      if (done == gridDim.x - 1) {
        float total = atomicAdd(loss_acc, 0.f);
        out[16777216] = 1.25f * total * (1.f / 16777216.f);
      }
    }
  }
  __syncthreads();

  // ---- phase 3: h = hidden + mask*code_out[idx]; LayerNorm; store ----
  {
    float4 g4 = *(const float4*)(gamma + lane * 4);
    float4 b4 = *(const float4*)(beta + lane * 4);
    for (int rr = 0; rr < 16; rr++) {
      int row = w * 16 + rr;
      int gr  = row0 + row;
      float4 h = *(const float4*)(hidden + (size_t)gr * 256 + lane * 4);
      int code = ridx[row];
      float4 o = *(const float4*)(code_out + (size_t)code * 256 + lane * 4);
      float mf = mask[gr] ? 1.f : 0.f;
      h.x += mf * o.x; h.y += mf * o.y; h.z += mf * o.z; h.w += mf * o.w;
      float s  = h.x + h.y + h.z + h.w;
      float sq = h.x * h.x + h.y * h.y + h.z * h.z + h.w * h.w;
      #pragma unroll
      for (int m = 1; m < 64; m <<= 1) { s += __shfl_xor(s, m); sq += __shfl_xor(sq, m); }
      float mean = s * (1.f / 256.f);
      float var  = sq * (1.f / 256.f) - mean * mean;
      float rstd = rsqrtf(var + LN_EPS);
      float4 res;
      res.x = (h.x - mean) * rstd * g4.x + b4.x;
      res.y = (h.y - mean) * rstd * g4.y + b4.y;
      res.z = (h.z - mean) * rstd * g4.z + b4.z;
      res.w = (h.w - mean) * rstd * g4.w + b4.w;
      *(float4*)(out + (size_t)gr * 256 + lane * 4) = res;
    }
  }
}

extern "C" void kernel_launch(void* const* d_in, const int* in_sizes, int n_in,
                              void* d_out, int out_size, void* d_ws, size_t ws_size,
                              hipStream_t stream) {
  (void)in_sizes; (void)n_in; (void)out_size; (void)ws_size;
  const float* hidden   = (const float*)d_in[0];
  const int*   mask     = (const int*)d_in[1];
  const float* codebook = (const float*)d_in[2];
  const float* W_in     = (const float*)d_in[3];
  const float* W_out    = (const float*)d_in[4];
  const float* gamma    = (const float*)d_in[5];
  const float* beta     = (const float*)d_in[6];
  float* out = (float*)d_out;

  float* wsf      = (float*)d_ws;
  float* loss_acc = wsf;                        // [1]
  unsigned* ticket = (unsigned*)(wsf + 1);      // [1]
  float* c2       = wsf + 64;                   // [512]
  float* code_out = wsf + 64 + 512;             // [512*256]
  unsigned short* BT = (unsigned short*)(wsf + 64 + 512 + 512 * 256); // 24*8192 bf16

  prep_kernel<<<352, 256, 0, stream>>>(codebook, W_in, W_out, loss_acc, ticket,
                                       c2, code_out, BT);
  main_kernel<<<1024, 256, 0, stream>>>(hidden, mask, gamma, beta, c2, code_out,
                                        BT, loss_acc, ticket, out);
}

// Round 6
// 187.260 us; speedup vs baseline: 1.1190x; 1.0494x over previous
//
#include <hip/hip_runtime.h>

#define LN_EPS 1e-5f

typedef short bf16x8 __attribute__((ext_vector_type(8)));
typedef float f32x4  __attribute__((ext_vector_type(4)));

__device__ __forceinline__ unsigned short f2bf(float f) {
  unsigned u = __float_as_uint(f);
  u += 0x7fffu + ((u >> 16) & 1u);          // RNE
  return (unsigned short)(u >> 16);
}
__device__ __forceinline__ float bf2f(unsigned short s) {
  return __uint_as_float(((unsigned)s) << 16);
}

__device__ __forceinline__ bf16x8 pack8(float4 a, float4 b) {
  bf16x8 v;
  v[0] = (short)f2bf(a.x); v[1] = (short)f2bf(a.y);
  v[2] = (short)f2bf(a.z); v[3] = (short)f2bf(a.w);
  v[4] = (short)f2bf(b.x); v[5] = (short)f2bf(b.y);
  v[6] = (short)f2bf(b.z); v[7] = (short)f2bf(b.w);
  return v;
}

// ---------------------------------------------------------------------------
// Prep (byte-identical to round 3): BT = pre-tiled bf16 image of
// [W_in: chunks 0..7 | CB: chunks 8..23], c2, code_out = CB@W_out^T,
// loss/ticket zero.
// ---------------------------------------------------------------------------
__global__ __launch_bounds__(256) void prep_kernel(
    const float* __restrict__ codebook, const float* __restrict__ W_in,
    const float* __restrict__ W_out,
    float* __restrict__ loss_acc, unsigned* __restrict__ ticket,
    float* __restrict__ c2, float* __restrict__ code_out,
    unsigned short* __restrict__ BT) {
  const int b = blockIdx.x, t = threadIdx.x;
  if (b < 32) {
    if (b == 0 && t == 0) { *loss_acc = 0.f; *ticket = 0u; }
    int e = b * 8 + (t >> 5);
    int c32 = t & 31, ks = c32 >> 2, kq = c32 & 3;
    const float* src = W_in + e * 256 + c32 * 8;
    float4 x0 = *(const float4*)src, x1 = *(const float4*)(src + 4);
    *(bf16x8*)(BT + ks * 8192 + (e >> 6) * 2048 + ((e >> 4) & 3) * 512 +
               kq * 128 + (e & 15) * 8) = pack8(x0, x1);
  } else if (b < 96) {
    int code = (b - 32) * 8 + (t >> 5);
    int c32 = t & 31, ks = c32 >> 2, kq = c32 & 3;
    const float* src = codebook + code * 256 + c32 * 8;
    float4 x0 = *(const float4*)src, x1 = *(const float4*)(src + 4);
    int cl = code & 255;
    int chunk = 8 + (code >> 8) * 8 + ks;
    *(bf16x8*)(BT + chunk * 8192 + (cl >> 6) * 2048 + ((cl >> 4) & 3) * 512 +
               kq * 128 + (cl & 15) * 8) = pack8(x0, x1);
    float s = x0.x * x0.x + x0.y * x0.y + x0.z * x0.z + x0.w * x0.w +
              x1.x * x1.x + x1.y * x1.y + x1.z * x1.z + x1.w * x1.w;
    s += __shfl_xor(s, 1);  s += __shfl_xor(s, 2);
    s += __shfl_xor(s, 4);  s += __shfl_xor(s, 8);
    s += __shfl_xor(s, 16);
    if ((t & 31) == 0) c2[code] = s;
  } else {
    __shared__ float Cs[32][260];
    __shared__ float Ws[16][260];
    int bi = b - 96, ci = bi & 15, ei = bi >> 4;
    {
      int row = t >> 4, col = (t & 15) * 16;
      const float4* s = (const float4*)(W_out + (size_t)(ei * 16 + row) * 256 + col);
      float4* d = (float4*)&Ws[row][col];
      d[0] = s[0]; d[1] = s[1]; d[2] = s[2]; d[3] = s[3];
    }
    {
      int row = t >> 3, col = (t & 7) * 32;
      const float4* s = (const float4*)(codebook + (size_t)(ci * 32 + row) * 256 + col);
      float4* d = (float4*)&Cs[row][col];
      #pragma unroll
      for (int k = 0; k < 8; k++) d[k] = s[k];
    }
    __syncthreads();
    int c = t & 31, e0 = t >> 5;
    float a0 = 0.f, a1 = 0.f;
    #pragma unroll 4
    for (int d = 0; d < 256; d += 4) {
      float4 cv = *(const float4*)&Cs[c][d];
      float4 w0 = *(const float4*)&Ws[e0][d];
      float4 w1 = *(const float4*)&Ws[e0 + 8][d];
      a0 += cv.x * w0.x + cv.y * w0.y + cv.z * w0.z + cv.w * w0.w;
      a1 += cv.x * w1.x + cv.y * w1.y + cv.z * w1.z + cv.w * w1.w;
    }
    code_out[(size_t)(ci * 32 + c) * 256 + ei * 16 + e0]     = a0;
    code_out[(size_t)(ci * 32 + c) * 256 + ei * 16 + e0 + 8] = a1;
  }
}

// ---------------------------------------------------------------------------
// Main fused kernel: round-3 structure, re-partitioned onto 8 thin waves
// (512 threads).  Each wave owns 32 code/e-columns (j in {0,1}); per-wave
// register state halves -> more resident waves -> latency hidden by TLP.
// No manual register rotation (r4/r5 failed on that).
// ---------------------------------------------------------------------------
__global__ __launch_bounds__(512, 4) void main_kernel(
    const float* __restrict__ hidden, const int* __restrict__ mask,
    const float* __restrict__ gamma, const float* __restrict__ beta,
    const float* __restrict__ c2g, const float* __restrict__ code_out,
    const unsigned short* __restrict__ BT,
    float* __restrict__ loss_acc, unsigned* __restrict__ ticket,
    float* __restrict__ out) {

  __shared__ unsigned short HZ[64 * 264];   // H then Z (33792 B), stride 264
  __shared__ float    z2[64];
  __shared__ unsigned sminp[512];
  __shared__ int      ridx[64];

  const int t    = threadIdx.x;             // 0..511
  const int lane = t & 63;
  const int w    = t >> 6;                  // wave 0..7
  const int l15  = lane & 15;
  const int quad = lane >> 4;
  const int row0 = blockIdx.x * 64;

  // c2 for this wave's 2x32 code columns
  float ccp[2][2];
  #pragma unroll
  for (int p = 0; p < 2; p++)
    #pragma unroll
    for (int j = 0; j < 2; j++)
      ccp[p][j] = c2g[p * 256 + w * 32 + j * 16 + l15];

  // ---- stage H: contiguous global reads, b128 LDS writes ----
  {
    #pragma unroll
    for (int i = 0; i < 4; i++) {
      int flat = (t * 8) + i * 4096;        // float index in 64x256 tile
      int r = flat >> 8, c = flat & 255;
      const float* src = hidden + (size_t)row0 * 256 + flat;
      float4 x0 = *(const float4*)src, x1 = *(const float4*)(src + 4);
      *(bf16x8*)(HZ + r * 264 + c) = pack8(x0, x1);
    }
  }
  __syncthreads();   // H visible

  const f32x4 zf = {0.f, 0.f, 0.f, 0.f};
  f32x4 acc[4][2];
  #pragma unroll
  for (int i = 0; i < 4; i++)
    #pragma unroll
    for (int j = 0; j < 2; j++) acc[i][j] = zf;

  // b-frag address: BT + chunk*8192 + w*1024 + j*512 + quad*128 + l15*8
  // (matches prep's layout for code/col c = w*32 + j*16 + l15)
  const unsigned short* BTw = BT + w * 1024 + lane * 8;

  // ---------------- Phase 1: Z = H * W_in^T ----------------
  #pragma unroll 2
  for (int ks = 0; ks < 8; ks++) {
    const unsigned short* bp = BTw + ks * 8192;
    bf16x8 b0 = *(const bf16x8*)(bp);
    bf16x8 b1 = *(const bf16x8*)(bp + 512);
    bf16x8 a[4];
    #pragma unroll
    for (int i = 0; i < 4; i++)
      a[i] = *(const bf16x8*)(HZ + (i * 16 + l15) * 264 + ks * 32 + quad * 8);
    #pragma unroll
    for (int i = 0; i < 4; i++) {
      acc[i][0] = __builtin_amdgcn_mfma_f32_16x16x32_bf16(a[i], b0, acc[i][0], 0, 0, 0);
      acc[i][1] = __builtin_amdgcn_mfma_f32_16x16x32_bf16(a[i], b1, acc[i][1], 0, 0, 0);
    }
  }

  __syncthreads();   // all H reads done
  // Z epilogue: C/D layout row = quad*4+reg, col = lane&15
  #pragma unroll
  for (int i = 0; i < 4; i++)
    #pragma unroll
    for (int j = 0; j < 2; j++)
      #pragma unroll
      for (int r = 0; r < 4; r++)
        HZ[(i * 16 + quad * 4 + r) * 264 + (w * 32 + j * 16 + l15)] =
            f2bf(acc[i][j][r]);
  __syncthreads();   // Z visible

  { // |z|^2 per row from bf16 Z (consistent with scores)
    int zr = t >> 3, part = t & 7;
    float s = 0.f;
    const unsigned short* zp = HZ + zr * 264 + part * 32;
    #pragma unroll
    for (int c = 0; c < 32; c += 8) {
      bf16x8 v = *(const bf16x8*)(zp + c);
      #pragma unroll
      for (int e = 0; e < 8; e++) { float f = bf2f((unsigned short)v[e]); s += f * f; }
    }
    s += __shfl_xor(s, 1);
    s += __shfl_xor(s, 2);
    s += __shfl_xor(s, 4);
    if (part == 0) z2[zr] = s;
  }

  // ---------------- Phase 2: scores + packed argmin ----------------
  unsigned runp[16];
  #pragma unroll
  for (int r = 0; r < 16; r++) runp[r] = 0xFFFFFFFFu;

  #pragma unroll
  for (int pass = 0; pass < 2; pass++) {
    #pragma unroll
    for (int i = 0; i < 4; i++)
      #pragma unroll
      for (int j = 0; j < 2; j++) acc[i][j] = zf;

    #pragma unroll 2
    for (int ks = 0; ks < 8; ks++) {
      const unsigned short* bp = BTw + (8 + pass * 8 + ks) * 8192;
      bf16x8 b0 = *(const bf16x8*)(bp);
      bf16x8 b1 = *(const bf16x8*)(bp + 512);
      bf16x8 a[4];
      #pragma unroll
      for (int i = 0; i < 4; i++)
        a[i] = *(const bf16x8*)(HZ + (i * 16 + l15) * 264 + ks * 32 + quad * 8);
      #pragma unroll
      for (int i = 0; i < 4; i++) {
        acc[i][0] = __builtin_amdgcn_mfma_f32_16x16x32_bf16(a[i], b0, acc[i][0], 0, 0, 0);
        acc[i][1] = __builtin_amdgcn_mfma_f32_16x16x32_bf16(a[i], b1, acc[i][1], 0, 0, 0);
      }
    }
    // fold: m = c2 - 2 z.c ; pack sortable (dist | 9-bit code); min
    #pragma unroll
    for (int i = 0; i < 4; i++)
      #pragma unroll
      for (int j = 0; j < 2; j++) {
        int code = pass * 256 + w * 32 + j * 16 + l15;
        float cc = ccp[pass][j];
        #pragma unroll
        for (int r = 0; r < 4; r++) {
          float m = cc - 2.f * acc[i][j][r];
          unsigned bits = __float_as_uint(m);
          unsigned u = bits ^ (0x80000000u | (unsigned)((int)bits >> 31));
          unsigned p = (u & 0xFFFFFE00u) | (unsigned)code;
          int ri = i * 4 + r;
          runp[ri] = min(runp[ri], p);
        }
      }
  }

  // reduce across the 16 lanes of each quad group
  #pragma unroll
  for (int ri = 0; ri < 16; ri++) {
    unsigned v = runp[ri];
    v = min(v, (unsigned)__shfl_xor((int)v, 1));
    v = min(v, (unsigned)__shfl_xor((int)v, 2));
    v = min(v, (unsigned)__shfl_xor((int)v, 4));
    v = min(v, (unsigned)__shfl_xor((int)v, 8));
    if (l15 == 0) {
      int i = ri >> 2, r = ri & 3;
      sminp[w * 64 + (i * 16 + quad * 4 + r)] = v;
    }
  }
  __syncthreads();

  if (t < 64) { // merge 8 waves, finalize idx + dist, block loss + ticket
    int row = t;
    unsigned bv = sminp[row];
    #pragma unroll
    for (int ww = 1; ww < 8; ww++) bv = min(bv, sminp[ww * 64 + row]);
    ridx[row] = (int)(bv & 511u);
    unsigned u = bv & 0xFFFFFE00u;
    unsigned bits = (u & 0x80000000u) ? (u ^ 0x80000000u) : ~u;
    float dist = z2[row] + __uint_as_float(bits);
    #pragma unroll
    for (int m = 1; m < 64; m <<= 1) dist += __shfl_xor(dist, m);
    if (t == 0) {
      atomicAdd(loss_acc, dist);
      __threadfence();
      unsigned done = atomicAdd(ticket, 1u);
      if (done == gridDim.x - 1) {
        float total = atomicAdd(loss_acc, 0.f);
        out[16777216] = 1.25f * total * (1.f / 16777216.f);
      }
    }
  }
  __syncthreads();

  // ---- phase 3: h = hidden + mask*code_out[idx]; LayerNorm; store ----
  {
    float4 g4 = *(const float4*)(gamma + lane * 4);
    float4 b4 = *(const float4*)(beta + lane * 4);
    for (int rr = 0; rr < 8; rr++) {
      int row = w * 8 + rr;
      int gr  = row0 + row;
      float4 h = *(const float4*)(hidden + (size_t)gr * 256 + lane * 4);
      int code = ridx[row];
      float4 o = *(const float4*)(code_out + (size_t)code * 256 + lane * 4);
      float mf = mask[gr] ? 1.f : 0.f;
      h.x += mf * o.x; h.y += mf * o.y; h.z += mf * o.z; h.w += mf * o.w;
      float s  = h.x + h.y + h.z + h.w;
      float sq = h.x * h.x + h.y * h.y + h.z * h.z + h.w * h.w;
      #pragma unroll
      for (int m = 1; m < 64; m <<= 1) { s += __shfl_xor(s, m); sq += __shfl_xor(sq, m); }
      float mean = s * (1.f / 256.f);
      float var  = sq * (1.f / 256.f) - mean * mean;
      float rstd = rsqrtf(var + LN_EPS);
      float4 res;
      res.x = (h.x - mean) * rstd * g4.x + b4.x;
      res.y = (h.y - mean) * rstd * g4.y + b4.y;
      res.z = (h.z - mean) * rstd * g4.z + b4.z;
      res.w = (h.w - mean) * rstd * g4.w + b4.w;
      *(float4*)(out + (size_t)gr * 256 + lane * 4) = res;
    }
  }
}

extern "C" void kernel_launch(void* const* d_in, const int* in_sizes, int n_in,
                              void* d_out, int out_size, void* d_ws, size_t ws_size,
                              hipStream_t stream) {
  (void)in_sizes; (void)n_in; (void)out_size; (void)ws_size;
  const float* hidden   = (const float*)d_in[0];
  const int*   mask     = (const int*)d_in[1];
  const float* codebook = (const float*)d_in[2];
  const float* W_in     = (const float*)d_in[3];
  const float* W_out    = (const float*)d_in[4];
  const float* gamma    = (const float*)d_in[5];
  const float* beta     = (const float*)d_in[6];
  float* out = (float*)d_out;

  float* wsf      = (float*)d_ws;
  float* loss_acc = wsf;                        // [1]
  unsigned* ticket = (unsigned*)(wsf + 1);      // [1]
  float* c2       = wsf + 64;                   // [512]
  float* code_out = wsf + 64 + 512;             // [512*256]
  unsigned short* BT = (unsigned short*)(wsf + 64 + 512 + 512 * 256); // 24*8192 bf16

  prep_kernel<<<352, 256, 0, stream>>>(codebook, W_in, W_out, loss_acc, ticket,
                                       c2, code_out, BT);
  main_kernel<<<1024, 512, 0, stream>>>(hidden, mask, gamma, beta, c2, code_out,
                                        BT, loss_acc, ticket, out);
}